// Round 1
// baseline (713.650 us; speedup 1.0000x reference)
//
#include <hip/hip_runtime.h>

#define N_NODES 50000
#define N_EDGES 600000
#define DIM 128
#define NBLK_MLP ((N_NODES + 127) / 128)   // 391

typedef __attribute__((ext_vector_type(8))) short s16x8;
typedef __attribute__((ext_vector_type(8))) unsigned short u16x8;
typedef __attribute__((ext_vector_type(4))) float f32x4;
typedef __attribute__((ext_vector_type(2))) float f32x2;

__device__ __forceinline__ unsigned short f2b(float f) {
    union { float f; unsigned int i; } v;
    v.f = f;
    unsigned int i = v.i;
    return (unsigned short)((i + 0x7FFFu + ((i >> 16) & 1u)) >> 16);
}

// pack 8 fp32 -> 8 bf16 (RNE)
__device__ __forceinline__ s16x8 cvt8(f32x4 a, f32x4 b) {
    union { u16x8 u; s16x8 s; } t;
#pragma unroll
    for (int j = 0; j < 4; j++) { t.u[j] = f2b(a[j]); t.u[4 + j] = f2b(b[j]); }
    return t.s;
}

// ---------------------------------------------------------------------------
// Phase A: CSR by destination (no per-element atomics), then gather-reduce.
// CSR scratch lives in d_out (dead until k_mlp overwrites it with h2).
//   off     int[50001]   @ byte 0
//   cursor  int[50000]   @ byte 200,064   (= count during k_hist)
//   pairs   int2[600000] @ byte 400,128   (4.8 MB: packed {eid, src})
// ---------------------------------------------------------------------------

// K0a: histogram of destinations
__global__ __launch_bounds__(256) void k_hist(
    const int* __restrict__ ei, int* __restrict__ count)
{
    int t = blockIdx.x * 256 + threadIdx.x;
    if (t < N_EDGES) atomicAdd(&count[ei[N_EDGES + t]], 1);
}

// K0b: exclusive scan of counts -> off[0..N]; cursor[v] = off[v] (in place)
__global__ __launch_bounds__(1024) void k_scan(
    int* __restrict__ off, int* cnt_cur)
{
    __shared__ int part[1024];
    const int CH = (N_NODES + 1023) / 1024;  // 49
    const int t = threadIdx.x;
    const int lo = t * CH;
    const int hi = (lo + CH < N_NODES) ? lo + CH : N_NODES;
    int s = 0;
    for (int v = lo; v < hi; v++) s += cnt_cur[v];
    part[t] = s;
    __syncthreads();
    for (int d = 1; d < 1024; d <<= 1) {
        int val = (t >= d) ? part[t - d] : 0;
        __syncthreads();
        part[t] += val;
        __syncthreads();
    }
    int run = (t == 0) ? 0 : part[t - 1];
    for (int v = lo; v < hi; v++) {
        int c = cnt_cur[v];
        off[v] = run;
        cnt_cur[v] = run;
        run += c;
    }
    if (t == 0) off[N_NODES] = N_EDGES;
}

// K0c: place packed {eid, src} into CSR slots (kills the dependent
// ei[eid] gather inside k_gather's hot loop)
__global__ __launch_bounds__(256) void k_scatter_ids(
    const int* __restrict__ ei, int* __restrict__ cursor,
    int2* __restrict__ pairs)
{
    int t = blockIdx.x * 256 + threadIdx.x;
    if (t < N_EDGES) {
        int src = ei[t];                 // coalesced
        int dst = ei[N_EDGES + t];       // coalesced
        int pos = atomicAdd(&cursor[dst], 1);
        int2 p; p.x = t; p.y = src;
        pairs[pos] = p;
    }
}

// K1: gather-reduce, 4 edges in flight per wave (16 lanes x 32B per edge).
// Per iteration: one 8B broadcast pair-load per group + 4x16B row loads per
// lane -> 4 KB outstanding per wave-iteration vs 1 KB (and 1 edge) before.
__global__ __launch_bounds__(256) void k_gather(
    const float* __restrict__ x,
    const float* __restrict__ ea,
    const int* __restrict__ off,
    const int2* __restrict__ pairs,
    float* __restrict__ agg)
{
    const int wave = threadIdx.x >> 6;
    const int lane = threadIdx.x & 63;
    const int g = lane >> 4;        // edge sub-group 0..3
    const int c = lane & 15;        // dims 8c .. 8c+7
    const int v = blockIdx.x * 4 + wave;
    if (v >= N_NODES) return;
    const int o0 = off[v], o1 = off[v + 1];
    f32x4 a0 = {0.f, 0.f, 0.f, 0.f};
    f32x4 a1 = {0.f, 0.f, 0.f, 0.f};
    for (int e = o0 + g; e < o1; e += 4) {
        int2 p = pairs[e];          // same addr across 16 lanes: HW broadcast
        const float* xr = x + (size_t)p.y * DIM + 8 * c;
        const float* er = ea + (size_t)p.x * DIM + 8 * c;
        f32x4 xv0 = *(const f32x4*)xr;
        f32x4 xv1 = *(const f32x4*)(xr + 4);
        f32x4 ev0 = __builtin_nontemporal_load((const f32x4*)er);      // ea streams once
        f32x4 ev1 = __builtin_nontemporal_load((const f32x4*)(er + 4));
#pragma unroll
        for (int j = 0; j < 4; j++) {
            a0[j] += fmaxf(xv0[j] + ev0[j], 0.f);
            a1[j] += fmaxf(xv1[j] + ev1[j], 0.f);
        }
    }
    // reduce the 4 edge-groups: lanes {c, c+16, c+32, c+48}
#pragma unroll
    for (int j = 0; j < 4; j++) {
        a0[j] += __shfl_xor(a0[j], 16); a0[j] += __shfl_xor(a0[j], 32);
        a1[j] += __shfl_xor(a1[j], 16); a1[j] += __shfl_xor(a1[j], 32);
    }
    if (g == 0) {
        float* o = agg + (size_t)v * DIM + 8 * c;
        *(f32x4*)o = a0;
        *(f32x4*)(o + 4) = a1;
    }
}

// ---------------------------------------------------------------------------
// K2: fused  h0 = bf16(x+agg);  h1 = relu(h0@w1^T+b1);  h2 = h1@w2^T+b2 (fp32)
// + per-block column sum/sumsq of h2 (BN stats) written into the block's OWN
// agg rows (r0_block, r0_block+1) -- already consumed, no aliasing hazard.
// ---------------------------------------------------------------------------
__global__ __launch_bounds__(256) void k_mlp(
    const float* __restrict__ x,
    const float* __restrict__ agg,
    const float* __restrict__ w1,
    const float* __restrict__ b1,
    const float* __restrict__ w2,
    const float* __restrict__ b2,
    float* __restrict__ h2out,
    float* __restrict__ pstat)   // == agg (non-const alias)
{
    __shared__ __align__(16) unsigned short lds[4][32][136];
    __shared__ float sm_s[4][DIM];
    __shared__ float sm_ss[4][DIM];
    const int wave = threadIdx.x >> 6;
    const int lane = threadIdx.x & 63;
    const int n = lane & 15;
    const int g = lane >> 4;
    const int r0 = blockIdx.x * 128 + wave * 32;
    // NOTE: no early return (syncthreads below needs all waves); OOB rows are
    // clamped on load and guarded on store/stats.

    s16x8 afrag[2][4];
#pragma unroll
    for (int tile = 0; tile < 2; tile++) {
        int row = r0 + tile * 16 + n;
        if (row > N_NODES - 1) row = N_NODES - 1;
        const float* xr = x + (size_t)row * DIM;
        const float* ar = agg + (size_t)row * DIM;
#pragma unroll
        for (int q = 0; q < 4; q++) {
            int k0 = 32 * q + 8 * g;
            f32x4 s0 = *(const f32x4*)(xr + k0);
            f32x4 s1 = *(const f32x4*)(xr + k0 + 4);
            f32x4 p0 = *(const f32x4*)(ar + k0);
            f32x4 p1 = *(const f32x4*)(ar + k0 + 4);
#pragma unroll
            for (int j = 0; j < 4; j++) { s0[j] += p0[j]; s1[j] += p1[j]; }
            afrag[tile][q] = cvt8(s0, s1);
        }
    }

#pragma unroll
    for (int t = 0; t < 8; t++) {
        f32x4 c0 = {0.f, 0.f, 0.f, 0.f};
        f32x4 c1 = {0.f, 0.f, 0.f, 0.f};
#pragma unroll
        for (int q = 0; q < 4; q++) {
            const float* wr = w1 + (16 * t + n) * DIM + 32 * q + 8 * g;
            s16x8 bfr = cvt8(*(const f32x4*)wr, *(const f32x4*)(wr + 4));
            c0 = __builtin_amdgcn_mfma_f32_16x16x32_bf16(afrag[0][q], bfr, c0, 0, 0, 0);
            c1 = __builtin_amdgcn_mfma_f32_16x16x32_bf16(afrag[1][q], bfr, c1, 0, 0, 0);
        }
        float bias = b1[16 * t + n];
#pragma unroll
        for (int rr = 0; rr < 4; rr++) {
            lds[wave][4 * g + rr][16 * t + n]      = f2b(fmaxf(c0[rr] + bias, 0.f));
            lds[wave][16 + 4 * g + rr][16 * t + n] = f2b(fmaxf(c1[rr] + bias, 0.f));
        }
    }

    s16x8 a2[2][4];
#pragma unroll
    for (int tile = 0; tile < 2; tile++) {
#pragma unroll
        for (int q = 0; q < 4; q++) {
            union { u16x8 u; s16x8 s; } tmp;
            tmp.u = *(const u16x8*)&lds[wave][tile * 16 + n][32 * q + 8 * g];
            a2[tile][q] = tmp.s;
        }
    }

#pragma unroll
    for (int t = 0; t < 8; t++) {
        f32x4 c0 = {0.f, 0.f, 0.f, 0.f};
        f32x4 c1 = {0.f, 0.f, 0.f, 0.f};
#pragma unroll
        for (int q = 0; q < 4; q++) {
            const float* wr = w2 + (16 * t + n) * DIM + 32 * q + 8 * g;
            s16x8 bfr = cvt8(*(const f32x4*)wr, *(const f32x4*)(wr + 4));
            c0 = __builtin_amdgcn_mfma_f32_16x16x32_bf16(a2[0][q], bfr, c0, 0, 0, 0);
            c1 = __builtin_amdgcn_mfma_f32_16x16x32_bf16(a2[1][q], bfr, c1, 0, 0, 0);
        }
        float bias = b2[16 * t + n];
        float cs = 0.f, css = 0.f;
#pragma unroll
        for (int rr = 0; rr < 4; rr++) {
            int row0 = r0 + 4 * g + rr;
            int row1 = r0 + 16 + 4 * g + rr;
            float v0 = c0[rr] + bias;
            float v1 = c1[rr] + bias;
            if (row0 < N_NODES) {
                h2out[(size_t)row0 * DIM + 16 * t + n] = v0;
                cs += v0; css += v0 * v0;
            }
            if (row1 < N_NODES) {
                h2out[(size_t)row1 * DIM + 16 * t + n] = v1;
                cs += v1; css += v1 * v1;
            }
        }
        // column 16t+n lives in lanes {n, n+16, n+32, n+48}
        cs  += __shfl_xor(cs, 16);  cs  += __shfl_xor(cs, 32);
        css += __shfl_xor(css, 16); css += __shfl_xor(css, 32);
        if (lane < 16) { sm_s[wave][16 * t + lane] = cs; sm_ss[wave][16 * t + lane] = css; }
    }

    __syncthreads();
    const int tid = threadIdx.x;
    if (tid < DIM) {
        float S  = sm_s[0][tid] + sm_s[1][tid] + sm_s[2][tid] + sm_s[3][tid];
        float SS = sm_ss[0][tid] + sm_ss[1][tid] + sm_ss[2][tid] + sm_ss[3][tid];
        float* ps = pstat + (size_t)blockIdx.x * 128 * DIM;  // agg row r0_block
        ps[tid]       = S;    // row r0_block
        ps[DIM + tid] = SS;   // row r0_block + 1
    }
}

// ---------------------------------------------------------------------------
// K3: BN finalize -- reduce 391 per-block partials, write scale/shift
// ---------------------------------------------------------------------------
__global__ __launch_bounds__(512) void k_bn_finalize(
    const float* __restrict__ pstat,
    const float* __restrict__ bnw, const float* __restrict__ bnb,
    float* __restrict__ scale, float* __restrict__ shiftv)
{
    __shared__ float as[4][DIM], ass[4][DIM];
    const int t = threadIdx.x;          // 512
    const int c = t & 127, q = t >> 7;  // 4 chunks of blocks
    float s = 0.f, ss = 0.f;
    for (int b = q; b < NBLK_MLP; b += 4) {
        const float* ps = pstat + (size_t)b * 128 * DIM;
        s += ps[c]; ss += ps[DIM + c];
    }
    as[q][c] = s; ass[q][c] = ss;
    __syncthreads();
    if (t < DIM) {
        float S  = as[0][t] + as[1][t] + as[2][t] + as[3][t];
        float SS = ass[0][t] + ass[1][t] + ass[2][t] + ass[3][t];
        const float invN = 1.0f / (float)N_NODES;
        float mean = S * invN;
        float var = fmaxf(SS * invN - mean * mean, 0.0f);
        float sc = bnw[t] * rsqrtf(var + 1e-5f);
        scale[t] = sc;
        shiftv[t] = bnb[t] - mean * sc;
    }
}

// ---------------------------------------------------------------------------
// K4: out = relu(h2*scale + shift), fp32 in place on d_out
// ---------------------------------------------------------------------------
__global__ __launch_bounds__(256) void k_bn_apply(
    float* __restrict__ h2,
    const float* __restrict__ scale, const float* __restrict__ shiftv)
{
    int t = blockIdx.x * 256 + threadIdx.x;
    int col0 = (t * 8) & (DIM - 1);
    float* p = h2 + (size_t)t * 8;
    f32x4 h0 = *(const f32x4*)p;
    f32x4 h1 = *(const f32x4*)(p + 4);
    f32x4 s0 = *(const f32x4*)(scale + col0);
    f32x4 s1 = *(const f32x4*)(scale + col0 + 4);
    f32x4 f0 = *(const f32x4*)(shiftv + col0);
    f32x4 f1 = *(const f32x4*)(shiftv + col0 + 4);
    f32x4 o0, o1;
#pragma unroll
    for (int j = 0; j < 4; j++) {
        o0[j] = fmaxf(fmaf(h0[j], s0[j], f0[j]), 0.0f);
        o1[j] = fmaxf(fmaf(h1[j], s1[j], f1[j]), 0.0f);
    }
    *(f32x4*)p = o0;
    *(f32x4*)(p + 4) = o1;
}

// ---------------------------------------------------------------------------
// Buffers:
//   ws (>= 25.6 MB): agg fp32[50000][128] at offset 0.
//     BN partials reuse agg rows {128b, 128b+1} per MLP block b (dead rows,
//     written only by the owning block after it consumed them).
//     scale @ byte 102400 (= agg row 200, dead), shift @ 102912 (row 201).
//   d_out (25.6 MB): phase A = CSR scratch (off / cursor / pairs), then k_mlp
//     overwrites with h2; K4 applies BN in place.
// ---------------------------------------------------------------------------
extern "C" void kernel_launch(void* const* d_in, const int* in_sizes, int n_in,
                              void* d_out, int out_size, void* d_ws, size_t ws_size,
                              hipStream_t stream) {
    const float* x   = (const float*)d_in[0];
    const int*   ei  = (const int*)d_in[1];
    const float* ea  = (const float*)d_in[2];
    const float* w1  = (const float*)d_in[3];
    const float* b1  = (const float*)d_in[4];
    const float* w2  = (const float*)d_in[5];
    const float* b2  = (const float*)d_in[6];
    const float* bnw = (const float*)d_in[7];
    const float* bnb = (const float*)d_in[8];

    char* ws = (char*)d_ws;
    float* agg     = (float*)ws;
    float* scale   = (float*)(ws + 102400);
    float* shiftv  = (float*)(ws + 102912);
    float* h2      = (float*)d_out;

    char* ob = (char*)d_out;
    int*  off    = (int*)ob;
    int*  cursor = (int*)(ob + 200064);   // doubles as count[] during k_hist
    int2* pairs  = (int2*)(ob + 400128);  // 8B-aligned (400128 % 8 == 0)

    // zero only the count/cursor region (200 KB); off[] fully written by scan,
    // pairs[] fully written by scatter.
    hipMemsetAsync(ob + 200064, 0, 200000, stream);

    k_hist<<<(N_EDGES + 255) / 256, 256, 0, stream>>>(ei, cursor);
    k_scan<<<1, 1024, 0, stream>>>(off, cursor);
    k_scatter_ids<<<(N_EDGES + 255) / 256, 256, 0, stream>>>(ei, cursor, pairs);
    k_gather<<<(N_NODES + 3) / 4, 256, 0, stream>>>(x, ea, off, pairs, agg);
    k_mlp<<<NBLK_MLP, 256, 0, stream>>>(x, agg, w1, b1, w2, b2, h2, agg);
    k_bn_finalize<<<1, 512, 0, stream>>>(agg, bnw, bnb, scale, shiftv);
    k_bn_apply<<<N_NODES * DIM / 8 / 256, 256, 0, stream>>>(h2, scale, shiftv);
}